// Round 4
// baseline (184.520 us; speedup 1.0000x reference)
//
#include <hip/hip_runtime.h>

typedef __bf16 bf16;
typedef __bf16 bf16x8 __attribute__((ext_vector_type(8)));
typedef __bf16 bf16x4 __attribute__((ext_vector_type(4)));
typedef float  f32x4  __attribute__((ext_vector_type(4)));

#define D_MODEL 1024
#define S_LEN   2048
#define NHEAD   16
#define DHEAD   64
#define BATCH   2
#define MROWS   (BATCH * S_LEN)   // 4096

// 0.125 (1/sqrt(dhead)) * log2(e): Q pre-scaled so softmax runs in exp2 domain
#define QSCALE 0.18033688011112042f

// ---- async global->LDS, 16B per lane. lds_base must be wave-uniform; HW
// writes lane i's data at lds_base + i*16 (guide §5 caveat).
__device__ __forceinline__ void gld_lds16(const void* g, void* lds_base) {
    __builtin_amdgcn_global_load_lds(
        (const __attribute__((address_space(1))) void*)g,
        (__attribute__((address_space(3))) void*)lds_base, 16, 0, 0);
}

// ============= prep: transpose+cast 4 weights (z<4) | cast x (z==4) ==========
__global__ void prep_kernel(const float* __restrict__ x,
                            const float* __restrict__ W0, const float* __restrict__ W1,
                            const float* __restrict__ W2, const float* __restrict__ W3,
                            bf16* __restrict__ xb, bf16* __restrict__ Wt) {
    int tx = threadIdx.x, ty = threadIdx.y;   // (32, 8)
    if (blockIdx.z == 4) {
        int tid = ty * 32 + tx;
        size_t base = ((size_t)blockIdx.y * 32 + blockIdx.x) * 4096;
#pragma unroll
        for (int j = 0; j < 4; j++) {
            size_t i = base + (size_t)(j * 256 + tid) * 4;
            f32x4 v = *(const f32x4*)(x + i);
            bf16x4 o;
            o[0] = (bf16)v[0]; o[1] = (bf16)v[1]; o[2] = (bf16)v[2]; o[3] = (bf16)v[3];
            *(bf16x4*)(xb + i) = o;
        }
        return;
    }
    __shared__ float tile[32][33];
    const float* W = (blockIdx.z == 0) ? W0 : (blockIdx.z == 1) ? W1
                   : (blockIdx.z == 2) ? W2 : W3;
    int n0 = blockIdx.x * 32, k0 = blockIdx.y * 32;
#pragma unroll
    for (int j = 0; j < 4; j++)
        tile[ty + 8 * j][tx] = W[(size_t)(k0 + ty + 8 * j) * D_MODEL + n0 + tx];
    __syncthreads();
    bf16* out = Wt + (size_t)blockIdx.z * D_MODEL * D_MODEL;
#pragma unroll
    for (int j = 0; j < 4; j++)
        out[(size_t)(n0 + ty + 8 * j) * D_MODEL + k0 + tx] = (bf16)tile[tx][ty + 8 * j];
}

// ===================== GEMM: C[M,N] = A[M,K] @ Bt[N,K]^T + bias ==============
// Pipelined single-barrier K-loop (T3-minimum 2-phase, same discipline as the
// attn kernel): double-buffered LDS, prologue stage(0); per step
//   [s_waitcnt vmcnt(0); s_barrier] -> stage(k+1) -> ds_read+MFMA(k)
// so next tile's global_load_lds fly under the current tile's MFMA, and there
// is ONE barrier per K-step instead of two (the old stage->sync->compute->sync
// structure had zero overlap: the documented ~20% drain stall).
// MODE 0 (QKV): BM=128 BN=128, 4 waves in 2x2, per-wave 64x64 (acc[4][4]).
// MODE 1 (out): BM=128 BN=64,  4 waves on M,   per-wave 32x64 (acc[2][4])
//   -> grid 16x32 = 512 blocks = 2 blocks/CU (the old 128x128 grid was 8x32
//   = 256 blocks = 1 block/CU = 1 wave/SIMD: no latency hiding at all).
template <int MODE>
__global__ __launch_bounds__(256, 3) void gemm_kernel(
    const bf16* __restrict__ A, const bf16* __restrict__ Bt,
    const float* __restrict__ b0, const float* __restrict__ b1, const float* __restrict__ b2,
    bf16* __restrict__ Qo, bf16* __restrict__ Ko, bf16* __restrict__ Vto,
    float* __restrict__ Co) {
    constexpr int BN = (MODE == 0) ? 128 : 64;
    constexpr int MI = (MODE == 0) ? 4 : 2;
    __shared__ bf16 sA[2][128 * 32];
    __shared__ bf16 sB[2][BN * 32];
    const int t = threadIdx.x;
    const int wave = t >> 6, lane = t & 63;
    const int quad = lane >> 4, m16 = lane & 15;
    const int wrow = (MODE == 0) ? (wave >> 1) * 64 : wave * 32;
    const int wcol = (MODE == 0) ? (wave & 1) * 64 : 0;
    const int row0 = blockIdx.y * 128, col0 = blockIdx.x * BN;
    const int K = D_MODEL;
    constexpr int NK = D_MODEL / 32;

    f32x4 acc[MI][4];
#pragma unroll
    for (int i = 0; i < MI; i++)
#pragma unroll
        for (int j = 0; j < 4; j++) acc[i][j] = (f32x4){0.f, 0.f, 0.f, 0.f};

    // stage K-step kk into buffer buf. A: 512 16B-chunks; B: BN*4 chunks.
    auto stage = [&](int kk, int buf) {
#pragma unroll
        for (int i = 0; i < 2; i++) {
            int cb = i * 256 + wave * 64;       // wave-uniform chunk base
            int c  = cb + lane;                 // this lane's 16B chunk
            int r  = c >> 2, kg = c & 3;        // tile row, k-group
            gld_lds16(A + (size_t)(row0 + r) * K + kk * 32 + kg * 8,
                      (char*)&sA[buf][0] + cb * 16);
        }
#pragma unroll
        for (int i = 0; i < BN / 64; i++) {
            int cb = i * 256 + wave * 64;
            int c  = cb + lane;
            int r  = c >> 2, kg = c & 3;
            gld_lds16(Bt + (size_t)(col0 + r) * K + kk * 32 + kg * 8,
                      (char*)&sB[buf][0] + cb * 16);
        }
    };

    stage(0, 0);

    for (int ks = 0; ks < NK; ++ks) {
        // own stage(ks) loads complete -> barrier => buf ks&1 fully staged for
        // all waves; barrier also means everyone finished READING buf (ks+1)&1
        // (consumed by compute ks-1), so stage(ks+1) may overwrite it.
        asm volatile("s_waitcnt vmcnt(0)\n\ts_barrier" ::: "memory");
        if (ks + 1 < NK) stage(ks + 1, (ks + 1) & 1);

        const int cur = ks & 1;
        bf16x8 af[MI], bfr[4];
#pragma unroll
        for (int mi = 0; mi < MI; mi++)
            af[mi] = *(const bf16x8*)&sA[cur][(wrow + mi * 16 + m16) * 32 + quad * 8];
#pragma unroll
        for (int ni = 0; ni < 4; ni++)
            bfr[ni] = *(const bf16x8*)&sB[cur][(wcol + ni * 16 + m16) * 32 + quad * 8];
#pragma unroll
        for (int mi = 0; mi < MI; mi++)
#pragma unroll
            for (int ni = 0; ni < 4; ni++)
                acc[mi][ni] = __builtin_amdgcn_mfma_f32_16x16x32_bf16(
                    af[mi], bfr[ni], acc[mi][ni], 0, 0, 0);
    }

    // epilogue. C/D layout: col = lane&15, row = quad*4 + reg (m89-verified).
    if (MODE == 1) {
#pragma unroll
        for (int mi = 0; mi < MI; mi++) {
            int r0 = row0 + wrow + mi * 16 + quad * 4;
#pragma unroll
            for (int ni = 0; ni < 4; ni++) {
                int col = col0 + wcol + ni * 16 + m16;
                float bias = b0[col];
#pragma unroll
                for (int r = 0; r < 4; r++)
                    Co[(size_t)(r0 + r) * D_MODEL + col] = acc[mi][ni][r] + bias;
            }
        }
    } else {
        int sel = col0 >> 10;   // uniform per block (1024 % 128 == 0)
        const float* bias_arr = (sel == 0) ? b0 : (sel == 1) ? b1 : b2;
#pragma unroll
        for (int mi = 0; mi < MI; mi++) {
            int s0g = row0 + wrow + mi * 16 + quad * 4;   // global M-row base
            int b = s0g >> 11, ss0 = s0g & 2047;
#pragma unroll
            for (int ni = 0; ni < 4; ni++) {
                int col = col0 + wcol + ni * 16 + m16;
                int cn = col & 1023;
                int h = cn >> 6, d = cn & 63;
                float bias = bias_arr[cn];
                if (sel < 2) {
                    bf16* dst = (sel == 0) ? Qo : Ko;
                    float scl = (sel == 0) ? QSCALE : 1.0f;
                    size_t base = (((size_t)b * NHEAD + h) * S_LEN);
#pragma unroll
                    for (int r = 0; r < 4; r++)
                        dst[(base + ss0 + r) * DHEAD + d] = (bf16)((acc[mi][ni][r] + bias) * scl);
                } else {
                    bf16x4 pk;
#pragma unroll
                    for (int r = 0; r < 4; r++) pk[r] = (bf16)(acc[mi][ni][r] + bias);
                    *(bf16x4*)(Vto + (((size_t)b * NHEAD + h) * DHEAD + d) * S_LEN + ss0) = pk;
                }
            }
        }
    }
}

// ======================= flash attention (causal) ============================
// One block per (head, q-tile): grid 32x32 = 1024 blocks -> 4 blocks/CU
// (the round-2 pairing pinned the grid at 512 = 2 blocks/CU; occupancy 16%
// was the bottleneck, not instruction count). Double-buffered KV staging
// (LDS 32KB -> 5 blocks/CU LDS-limit, grid-limited at 4), prefetch depth 1:
// per tile: [waitcnt own loads -> barrier] -> stage(j+1) -> compute(j), so
// the next tile's loads fly under the current tile's compute.
// Grid mapping: x = head  => linear bid % 8 == head % 8 -> each XCD serves
// 4 heads, KV working set 4x512KB = 2MB < 4MB L2 (tile re-reads become L2
// hits). y = 31 - qt => largest q-tiles dispatch first (LPT backfill).
// Transposed scores (q = lane&15) -> per-lane softmax, no running max
// (exp2-domain |s| < ~6). P never touches LDS: scores packed to bf16 dwords
// in-register, redistributed to the NATURAL k-order B-fragment with a
// p32+p16 double swap; V-fragment is the conflict-tuned ds_read_b128 from
// the XOR-swizzled Vt_s (bank conflicts measured 0).
__global__ __launch_bounds__(256, 4) void attn_kernel(
    const bf16* __restrict__ Q, const bf16* __restrict__ K,
    const bf16* __restrict__ Vt, bf16* __restrict__ ctx) {
    __shared__ bf16 Kt_s[2][64 * 64];
    __shared__ bf16 Vt_s[2][64 * 64];

    const int t = threadIdx.x, wave = t >> 6, lane = t & 63;
    const int quad = lane >> 4, m16 = lane & 15;
    const int bh = blockIdx.x;            // head -> XCD bh%8 (L2 KV locality)
    const int qt = 31 - blockIdx.y;       // big tiles first (LPT)
    const int nt = qt + 1;                // causal KV tiles (64-wide)
    const size_t base = (size_t)bh * S_LEN * DHEAD;

    // Q fragments (B-operand), kept in regs
    bf16x8 aq[2];
#pragma unroll
    for (int kst = 0; kst < 2; kst++)
        aq[kst] = *(const bf16x8*)(Q + base
            + (size_t)(qt * 64 + wave * 16 + m16) * DHEAD + kst * 32 + quad * 8);

    f32x4 o[4];
#pragma unroll
    for (int di = 0; di < 4; di++) o[di] = (f32x4){0.f, 0.f, 0.f, 0.f};
    float l_acc = 0.f;

    // stage KV tile j into buffer buf (XOR chunk swizzle vs bank conflicts);
    // 4 VMEM instructions per wave.
    auto stage = [&](int j, int buf) {
#pragma unroll
        for (int i = 0; i < 2; i++) {
            int cb = i * 256 + wave * 64;
            int c  = cb + lane;
            int pos = c >> 3, g = c & 7;
            int gk = g ^ (pos & 7);
            gld_lds16(K  + base + (size_t)(j * 64 + pos) * DHEAD + gk * 8,
                      (char*)&Kt_s[buf][0] + cb * 16);
            gld_lds16(Vt + base + (size_t)pos * S_LEN + j * 64 + gk * 8,
                      (char*)&Vt_s[buf][0] + cb * 16);
        }
    };

    stage(0, 0);

    for (int j = 0; j < nt; ++j) {
        // own tile-j loads done BEFORE barrier => after barrier, everyone's
        // tile-j data is in LDS. Barrier also means everyone is done reading
        // buf[(j+1)&1] (used by compute j-1), so stage(j+1) may overwrite it.
        asm volatile("s_waitcnt vmcnt(0)\n\ts_barrier" ::: "memory");
        if (j + 1 < nt) stage(j + 1, (j + 1) & 1);

        const int cur = j & 1;
        const int kt0 = j * 64;

        // ---- scores S^T[kpos][q] = K @ Q^T
        f32x4 sc[4];
#pragma unroll
        for (int ni = 0; ni < 4; ni++) sc[ni] = (f32x4){0.f, 0.f, 0.f, 0.f};
        __builtin_amdgcn_s_setprio(1);
#pragma unroll
        for (int ni = 0; ni < 4; ni++) {
            int pos = ni * 16 + m16;
#pragma unroll
            for (int kst = 0; kst < 2; kst++) {
                int gg = (kst * 4 + quad) ^ (pos & 7);
                bf16x8 kf = *(const bf16x8*)&Kt_s[cur][pos * 64 + gg * 8];
                sc[ni] = __builtin_amdgcn_mfma_f32_16x16x32_bf16(
                    kf, aq[kst], sc[ni], 0, 0, 0);
            }
        }
        __builtin_amdgcn_s_setprio(0);

        // ---- causal mask: only on the diagonal tile
        if (j == qt) {
            int qg = qt * 64 + wave * 16 + m16;
#pragma unroll
            for (int ni = 0; ni < 4; ni++)
#pragma unroll
                for (int r = 0; r < 4; r++) {
                    int kp = kt0 + ni * 16 + quad * 4 + r;
                    if (kp > qg) sc[ni][r] = -1e9f;
                }
        }

        // ---- p = exp2(s); accumulate l; pack bf16 dwords in-register.
        // sc[ni][r] at lane (srcq,m16) = P[q=m16][kpos=ni*16+srcq*4+r]
        unsigned int pd[4][2];
        {
            float ls0 = 0.f, ls1 = 0.f;
#pragma unroll
            for (int ni = 0; ni < 4; ni++) {
                float p0 = __builtin_amdgcn_exp2f(sc[ni][0]);
                float p1 = __builtin_amdgcn_exp2f(sc[ni][1]);
                float p2 = __builtin_amdgcn_exp2f(sc[ni][2]);
                float p3 = __builtin_amdgcn_exp2f(sc[ni][3]);
                union { bf16x4 h; unsigned int u[2]; } cv;
                cv.h[0] = (bf16)p0; cv.h[1] = (bf16)p1;
                cv.h[2] = (bf16)p2; cv.h[3] = (bf16)p3;
                pd[ni][0] = cv.u[0];
                pd[ni][1] = cv.u[1];
                ls0 += p0 + p1;
                ls1 += p2 + p3;
            }
            l_acc += ls0 + ls1;
        }

        // ---- O^T += (P @ V)^T = mfma(A=V^T frag, B=P frag), natural k order
        // restored via p32+p16 double swap:
        //   after p32: x0={ni0@srcq01|ni1@srcq01}, x1={ni0@srcq23|ni1@srcq23}
        //   after p16: dest quad q' holds contiguous kpos run {8q'..8q'+7},
        //              dword order [x0,y0,x1,y1]
#pragma unroll
        for (int kst = 0; kst < 2; kst++) {
            unsigned int x0 = pd[2 * kst][0],     y0 = pd[2 * kst][1];
            unsigned int x1 = pd[2 * kst + 1][0], y1 = pd[2 * kst + 1][1];
            asm("v_permlane32_swap_b32 %0, %1" : "+v"(x0), "+v"(x1));
            asm("v_permlane32_swap_b32 %0, %1" : "+v"(y0), "+v"(y1));
            asm("v_permlane16_swap_b32 %0, %1" : "+v"(x0), "+v"(x1));
            asm("v_permlane16_swap_b32 %0, %1" : "+v"(y0), "+v"(y1));
            union { unsigned int u[4]; bf16x8 v; } pk;
            pk.u[0] = x0; pk.u[1] = y0; pk.u[2] = x1; pk.u[3] = y1;
            bf16x8 ap = pk.v;
            __builtin_amdgcn_s_setprio(1);
#pragma unroll
            for (int di = 0; di < 4; di++) {
                int d = di * 16 + m16;
                int gg = (kst * 4 + quad) ^ (d & 7);
                bf16x8 vf = *(const bf16x8*)&Vt_s[cur][d * 64 + gg * 8];
                o[di] = __builtin_amdgcn_mfma_f32_16x16x32_bf16(
                    vf, ap, o[di], 0, 0, 0);
            }
            __builtin_amdgcn_s_setprio(0);
        }
    }

    // ---- final l reduction + normalize + write ctx [B,S,1024] bf16
    int b = bh >> 4, h = bh & 15;
    float l = l_acc;
    l += __shfl_xor(l, 16);
    l += __shfl_xor(l, 32);
    float rl = 1.0f / l;
    int s = qt * 64 + wave * 16 + m16;
#pragma unroll
    for (int di = 0; di < 4; di++) {
        bf16x4 pk;
#pragma unroll
        for (int r = 0; r < 4; r++) pk[r] = (bf16)(o[di][r] * rl);
        *(bf16x4*)(ctx + ((size_t)b * S_LEN + s) * D_MODEL
                   + h * DHEAD + di * 16 + quad * 4) = pk;
    }
}

// ================================ launch =====================================
extern "C" void kernel_launch(void* const* d_in, const int* in_sizes, int n_in,
                              void* d_out, int out_size, void* d_ws, size_t ws_size,
                              hipStream_t stream) {
    const float* x  = (const float*)d_in[0];
    const float* Wq = (const float*)d_in[1];
    const float* bq = (const float*)d_in[2];
    const float* Wk = (const float*)d_in[3];
    const float* bk = (const float*)d_in[4];
    const float* Wv = (const float*)d_in[5];
    const float* bv = (const float*)d_in[6];
    const float* Wo = (const float*)d_in[7];
    const float* bo = (const float*)d_in[8];
    float* out = (float*)d_out;

    char* ws = (char*)d_ws;
    const size_t MB = 1u << 20;
    bf16* xb  = (bf16*)(ws + 0);         // 8 MB  [4096,1024]
    bf16* Wt  = (bf16*)(ws + 8  * MB);   // 8 MB  [4][1024][1024]
    bf16* Qb  = (bf16*)(ws + 16 * MB);   // 8 MB  [B,H,S,64]  (pre-scaled by QSCALE)
    bf16* Kb  = (bf16*)(ws + 24 * MB);   // 8 MB  [B,H,S,64]
    bf16* Vtb = (bf16*)(ws + 32 * MB);   // 8 MB  [B,H,64,S]
    bf16* ctx = (bf16*)(ws + 0);         // reuse xb region (dead after QKV GEMM)

    prep_kernel<<<dim3(32, 32, 5), dim3(32, 8), 0, stream>>>(x, Wq, Wk, Wv, Wo, xb, Wt);
    gemm_kernel<0><<<dim3(24, 32), 256, 0, stream>>>(xb, Wt, bq, bk, bv,
                                                     Qb, Kb, Vtb, nullptr);
    attn_kernel<<<dim3(32, 32), 256, 0, stream>>>(Qb, Kb, Vtb, ctx);
    gemm_kernel<1><<<dim3(16, 32), 256, 0, stream>>>(ctx, Wt + 3 * 1024 * 1024,
                                                     bo, nullptr, nullptr,
                                                     nullptr, nullptr, nullptr, out);
}

// Round 6
// 178.804 us; speedup vs baseline: 1.0320x; 1.0320x over previous
//
#include <hip/hip_runtime.h>

typedef __bf16 bf16;
typedef __bf16 bf16x8 __attribute__((ext_vector_type(8)));
typedef __bf16 bf16x4 __attribute__((ext_vector_type(4)));
typedef float  f32x4  __attribute__((ext_vector_type(4)));

#define D_MODEL 1024
#define S_LEN   2048
#define NHEAD   16
#define DHEAD   64
#define BATCH   2
#define MROWS   (BATCH * S_LEN)   // 4096

// 0.125 (1/sqrt(dhead)) * log2(e): Q pre-scaled so softmax runs in exp2 domain
#define QSCALE 0.18033688011112042f

// ---- async global->LDS, 16B per lane. lds_base must be wave-uniform; HW
// writes lane i's data at lds_base + i*16 (guide §5 caveat).
__device__ __forceinline__ void gld_lds16(const void* g, void* lds_base) {
    __builtin_amdgcn_global_load_lds(
        (const __attribute__((address_space(1))) void*)g,
        (__attribute__((address_space(3))) void*)lds_base, 16, 0, 0);
}

// ============= prep: transpose+cast 4 weights (z<4) | cast x (z==4) ==========
__global__ void prep_kernel(const float* __restrict__ x,
                            const float* __restrict__ W0, const float* __restrict__ W1,
                            const float* __restrict__ W2, const float* __restrict__ W3,
                            bf16* __restrict__ xb, bf16* __restrict__ Wt) {
    int tx = threadIdx.x, ty = threadIdx.y;   // (32, 8)
    if (blockIdx.z == 4) {
        int tid = ty * 32 + tx;
        size_t base = ((size_t)blockIdx.y * 32 + blockIdx.x) * 4096;
#pragma unroll
        for (int j = 0; j < 4; j++) {
            size_t i = base + (size_t)(j * 256 + tid) * 4;
            f32x4 v = *(const f32x4*)(x + i);
            bf16x4 o;
            o[0] = (bf16)v[0]; o[1] = (bf16)v[1]; o[2] = (bf16)v[2]; o[3] = (bf16)v[3];
            *(bf16x4*)(xb + i) = o;
        }
        return;
    }
    __shared__ float tile[32][33];
    const float* W = (blockIdx.z == 0) ? W0 : (blockIdx.z == 1) ? W1
                   : (blockIdx.z == 2) ? W2 : W3;
    int n0 = blockIdx.x * 32, k0 = blockIdx.y * 32;
#pragma unroll
    for (int j = 0; j < 4; j++)
        tile[ty + 8 * j][tx] = W[(size_t)(k0 + ty + 8 * j) * D_MODEL + n0 + tx];
    __syncthreads();
    bf16* out = Wt + (size_t)blockIdx.z * D_MODEL * D_MODEL;
#pragma unroll
    for (int j = 0; j < 4; j++)
        out[(size_t)(n0 + ty + 8 * j) * D_MODEL + k0 + tx] = (bf16)tile[tx][ty + 8 * j];
}

// ===================== GEMM: C[M,N] = A[M,K] @ Bt[N,K]^T + bias ==============
// Triple-buffered K-loop, prefetch depth 2 with COUNTED vmcnt (the round-0
// attn discipline): per step
//   [s_waitcnt vmcnt(L); s_barrier] -> stage(ks+2) -> ds_read+MFMA(ks)
// (L = loads/stage: own stage(ks) is complete, newest stage(ks+1) stays in
// flight across the barrier). Depth-1+vmcnt(0) measured ~no gain in round 4:
// it still exposed (load latency - one compute phase) every step.
// LDS fragment-read swizzle vs bank conflicts (round-4 counters: 3.15M/disp):
// LDS phases b128 wave-reads 16 lanes (= one quad) at a time; the linear
// layout gave bank-starts 16*(row&1)+4*quad = 2 banks x 8 lanes = 8-way.
// Staging pre-swizzles the GLOBAL k-group (LDS dest stays linear, required
// by global_load_lds): slot kg of row r holds k-group kg ^ ((r>>1)&3); the
// read slot is quad ^ ((m16>>1)&3) -> per-phase bank-starts all 8 values x
// 2 lanes = 2-way = free (same arithmetic as the attn K/V pattern, which
// measures zero conflicts).
// MODE 0 (QKV): BM=128 BN=128, 4 waves in 2x2, per-wave 64x64 (acc[4][4]).
// MODE 1 (out): BM=128 BN=64,  4 waves on M,   per-wave 32x64 (acc[2][4]).
template <int MODE>
__global__ __launch_bounds__(256, 3) void gemm_kernel(
    const bf16* __restrict__ A, const bf16* __restrict__ Bt,
    const float* __restrict__ b0, const float* __restrict__ b1, const float* __restrict__ b2,
    bf16* __restrict__ Qo, bf16* __restrict__ Ko, bf16* __restrict__ Vto,
    float* __restrict__ Co) {
    constexpr int BN = (MODE == 0) ? 128 : 64;
    constexpr int MI = (MODE == 0) ? 4 : 2;
    __shared__ bf16 sA[3][128 * 32];
    __shared__ bf16 sB[3][BN * 32];
    const int t = threadIdx.x;
    const int wave = t >> 6, lane = t & 63;
    const int quad = lane >> 4, m16 = lane & 15;
    const int wrow = (MODE == 0) ? (wave >> 1) * 64 : wave * 32;
    const int wcol = (MODE == 0) ? (wave & 1) * 64 : 0;
    const int row0 = blockIdx.y * 128, col0 = blockIdx.x * BN;
    const int K = D_MODEL;
    constexpr int NK = D_MODEL / 32;

    f32x4 acc[MI][4];
#pragma unroll
    for (int i = 0; i < MI; i++)
#pragma unroll
        for (int j = 0; j < 4; j++) acc[i][j] = (f32x4){0.f, 0.f, 0.f, 0.f};

    // stage K-step kk into buffer buf; global k-group pre-swizzled so the
    // linear LDS slot kg of row r holds k-group kg ^ ((r>>1)&3).
    auto stage = [&](int kk, int buf) {
#pragma unroll
        for (int i = 0; i < 2; i++) {
            int cb = i * 256 + wave * 64;       // wave-uniform chunk base
            int c  = cb + lane;                 // this lane's 16B chunk
            int r  = c >> 2, kg = c & 3;        // tile row, LDS slot
            int gk = kg ^ ((r >> 1) & 3);       // swizzled global k-group
            gld_lds16(A + (size_t)(row0 + r) * K + kk * 32 + gk * 8,
                      (char*)&sA[buf][0] + cb * 16);
        }
#pragma unroll
        for (int i = 0; i < BN / 64; i++) {
            int cb = i * 256 + wave * 64;
            int c  = cb + lane;
            int r  = c >> 2, kg = c & 3;
            int gk = kg ^ ((r >> 1) & 3);
            gld_lds16(Bt + (size_t)(col0 + r) * K + kk * 32 + gk * 8,
                      (char*)&sB[buf][0] + cb * 16);
        }
    };

    stage(0, 0);
    stage(1, 1);

    const int sx = (m16 >> 1) & 3;    // row-derived slot swizzle (wave-inv.)
    for (int ks = 0; ks < NK; ++ks) {
        // own stage(ks) loads complete (newest prefetch stays in flight) ->
        // barrier => buf ks%3 fully staged for all waves; barrier also means
        // everyone finished READING buf (ks+2)%3 (consumed by compute ks-1),
        // so stage(ks+2) may overwrite it.
        if (ks + 1 < NK) {
            if constexpr (MODE == 0)
                asm volatile("s_waitcnt vmcnt(4)\n\ts_barrier" ::: "memory");
            else
                asm volatile("s_waitcnt vmcnt(3)\n\ts_barrier" ::: "memory");
        } else {
            asm volatile("s_waitcnt vmcnt(0)\n\ts_barrier" ::: "memory");
        }
        if (ks + 2 < NK) stage(ks + 2, (ks + 2) % 3);

        const int cur = ks % 3;
        const int gg = (quad ^ sx) * 8;
        bf16x8 af[MI], bfr[4];
#pragma unroll
        for (int mi = 0; mi < MI; mi++)
            af[mi] = *(const bf16x8*)&sA[cur][(wrow + mi * 16 + m16) * 32 + gg];
#pragma unroll
        for (int ni = 0; ni < 4; ni++)
            bfr[ni] = *(const bf16x8*)&sB[cur][(wcol + ni * 16 + m16) * 32 + gg];
#pragma unroll
        for (int mi = 0; mi < MI; mi++)
#pragma unroll
            for (int ni = 0; ni < 4; ni++)
                acc[mi][ni] = __builtin_amdgcn_mfma_f32_16x16x32_bf16(
                    af[mi], bfr[ni], acc[mi][ni], 0, 0, 0);
    }

    // epilogue. C/D layout: col = lane&15, row = quad*4 + reg (m89-verified).
    if (MODE == 1) {
#pragma unroll
        for (int mi = 0; mi < MI; mi++) {
            int r0 = row0 + wrow + mi * 16 + quad * 4;
#pragma unroll
            for (int ni = 0; ni < 4; ni++) {
                int col = col0 + wcol + ni * 16 + m16;
                float bias = b0[col];
#pragma unroll
                for (int r = 0; r < 4; r++)
                    Co[(size_t)(r0 + r) * D_MODEL + col] = acc[mi][ni][r] + bias;
            }
        }
    } else {
        int sel = col0 >> 10;   // uniform per block (1024 % 128 == 0)
        const float* bias_arr = (sel == 0) ? b0 : (sel == 1) ? b1 : b2;
#pragma unroll
        for (int mi = 0; mi < MI; mi++) {
            int s0g = row0 + wrow + mi * 16 + quad * 4;   // global M-row base
            int b = s0g >> 11, ss0 = s0g & 2047;
#pragma unroll
            for (int ni = 0; ni < 4; ni++) {
                int col = col0 + wcol + ni * 16 + m16;
                int cn = col & 1023;
                int h = cn >> 6, d = cn & 63;
                float bias = bias_arr[cn];
                if (sel < 2) {
                    bf16* dst = (sel == 0) ? Qo : Ko;
                    float scl = (sel == 0) ? QSCALE : 1.0f;
                    size_t base = (((size_t)b * NHEAD + h) * S_LEN);
#pragma unroll
                    for (int r = 0; r < 4; r++)
                        dst[(base + ss0 + r) * DHEAD + d] = (bf16)((acc[mi][ni][r] + bias) * scl);
                } else {
                    bf16x4 pk;
#pragma unroll
                    for (int r = 0; r < 4; r++) pk[r] = (bf16)(acc[mi][ni][r] + bias);
                    *(bf16x4*)(Vto + (((size_t)b * NHEAD + h) * DHEAD + d) * S_LEN + ss0) = pk;
                }
            }
        }
    }
}

// ======================= flash attention (causal) ============================
// One block per (head, q-tile): grid 32x32 = 1024 blocks -> 4 blocks/CU
// (the round-2 pairing pinned the grid at 512 = 2 blocks/CU; occupancy 16%
// was the bottleneck, not instruction count). Double-buffered KV staging
// (LDS 32KB -> 5 blocks/CU LDS-limit, grid-limited at 4), prefetch depth 1:
// per tile: [waitcnt own loads -> barrier] -> stage(j+1) -> compute(j), so
// the next tile's loads fly under the current tile's compute.
// Grid mapping: x = head  => linear bid % 8 == head % 8 -> each XCD serves
// 4 heads, KV working set 4x512KB = 2MB < 4MB L2 (tile re-reads become L2
// hits). y = 31 - qt => largest q-tiles dispatch first (LPT backfill).
// Transposed scores (q = lane&15) -> per-lane softmax, no running max
// (exp2-domain |s| < ~6). P never touches LDS: scores packed to bf16 dwords
// in-register, redistributed to the NATURAL k-order B-fragment with a
// p32+p16 double swap; V-fragment is the conflict-tuned ds_read_b128 from
// the XOR-swizzled Vt_s (bank conflicts measured 0).
__global__ __launch_bounds__(256, 4) void attn_kernel(
    const bf16* __restrict__ Q, const bf16* __restrict__ K,
    const bf16* __restrict__ Vt, bf16* __restrict__ ctx) {
    __shared__ bf16 Kt_s[2][64 * 64];
    __shared__ bf16 Vt_s[2][64 * 64];

    const int t = threadIdx.x, wave = t >> 6, lane = t & 63;
    const int quad = lane >> 4, m16 = lane & 15;
    const int bh = blockIdx.x;            // head -> XCD bh%8 (L2 KV locality)
    const int qt = 31 - blockIdx.y;       // big tiles first (LPT)
    const int nt = qt + 1;                // causal KV tiles (64-wide)
    const size_t base = (size_t)bh * S_LEN * DHEAD;

    // Q fragments (B-operand), kept in regs
    bf16x8 aq[2];
#pragma unroll
    for (int kst = 0; kst < 2; kst++)
        aq[kst] = *(const bf16x8*)(Q + base
            + (size_t)(qt * 64 + wave * 16 + m16) * DHEAD + kst * 32 + quad * 8);

    f32x4 o[4];
#pragma unroll
    for (int di = 0; di < 4; di++) o[di] = (f32x4){0.f, 0.f, 0.f, 0.f};
    float l_acc = 0.f;

    // stage KV tile j into buffer buf (XOR chunk swizzle vs bank conflicts);
    // 4 VMEM instructions per wave.
    auto stage = [&](int j, int buf) {
#pragma unroll
        for (int i = 0; i < 2; i++) {
            int cb = i * 256 + wave * 64;
            int c  = cb + lane;
            int pos = c >> 3, g = c & 7;
            int gk = g ^ (pos & 7);
            gld_lds16(K  + base + (size_t)(j * 64 + pos) * DHEAD + gk * 8,
                      (char*)&Kt_s[buf][0] + cb * 16);
            gld_lds16(Vt + base + (size_t)pos * S_LEN + j * 64 + gk * 8,
                      (char*)&Vt_s[buf][0] + cb * 16);
        }
    };

    stage(0, 0);

    for (int j = 0; j < nt; ++j) {
        // own tile-j loads done BEFORE barrier => after barrier, everyone's
        // tile-j data is in LDS. Barrier also means everyone is done reading
        // buf[(j+1)&1] (used by compute j-1), so stage(j+1) may overwrite it.
        asm volatile("s_waitcnt vmcnt(0)\n\ts_barrier" ::: "memory");
        if (j + 1 < nt) stage(j + 1, (j + 1) & 1);

        const int cur = j & 1;
        const int kt0 = j * 64;

        // ---- scores S^T[kpos][q] = K @ Q^T
        f32x4 sc[4];
#pragma unroll
        for (int ni = 0; ni < 4; ni++) sc[ni] = (f32x4){0.f, 0.f, 0.f, 0.f};
        __builtin_amdgcn_s_setprio(1);
#pragma unroll
        for (int ni = 0; ni < 4; ni++) {
            int pos = ni * 16 + m16;
#pragma unroll
            for (int kst = 0; kst < 2; kst++) {
                int gg = (kst * 4 + quad) ^ (pos & 7);
                bf16x8 kf = *(const bf16x8*)&Kt_s[cur][pos * 64 + gg * 8];
                sc[ni] = __builtin_amdgcn_mfma_f32_16x16x32_bf16(
                    kf, aq[kst], sc[ni], 0, 0, 0);
            }
        }
        __builtin_amdgcn_s_setprio(0);

        // ---- causal mask: only on the diagonal tile
        if (j == qt) {
            int qg = qt * 64 + wave * 16 + m16;
#pragma unroll
            for (int ni = 0; ni < 4; ni++)
#pragma unroll
                for (int r = 0; r < 4; r++) {
                    int kp = kt0 + ni * 16 + quad * 4 + r;
                    if (kp > qg) sc[ni][r] = -1e9f;
                }
        }

        // ---- p = exp2(s); accumulate l; pack bf16 dwords in-register.
        // sc[ni][r] at lane (srcq,m16) = P[q=m16][kpos=ni*16+srcq*4+r]
        unsigned int pd[4][2];
        {
            float ls0 = 0.f, ls1 = 0.f;
#pragma unroll
            for (int ni = 0; ni < 4; ni++) {
                float p0 = __builtin_amdgcn_exp2f(sc[ni][0]);
                float p1 = __builtin_amdgcn_exp2f(sc[ni][1]);
                float p2 = __builtin_amdgcn_exp2f(sc[ni][2]);
                float p3 = __builtin_amdgcn_exp2f(sc[ni][3]);
                union { bf16x4 h; unsigned int u[2]; } cv;
                cv.h[0] = (bf16)p0; cv.h[1] = (bf16)p1;
                cv.h[2] = (bf16)p2; cv.h[3] = (bf16)p3;
                pd[ni][0] = cv.u[0];
                pd[ni][1] = cv.u[1];
                ls0 += p0 + p1;
                ls1 += p2 + p3;
            }
            l_acc += ls0 + ls1;
        }

        // ---- O^T += (P @ V)^T = mfma(A=V^T frag, B=P frag), natural k order
        // restored via p32+p16 double swap:
        //   after p32: x0={ni0@srcq01|ni1@srcq01}, x1={ni0@srcq23|ni1@srcq23}
        //   after p16: dest quad q' holds contiguous kpos run {8q'..8q'+7},
        //              dword order [x0,y0,x1,y1]
#pragma unroll
        for (int kst = 0; kst < 2; kst++) {
            unsigned int x0 = pd[2 * kst][0],     y0 = pd[2 * kst][1];
            unsigned int x1 = pd[2 * kst + 1][0], y1 = pd[2 * kst + 1][1];
            asm("v_permlane32_swap_b32 %0, %1" : "+v"(x0), "+v"(x1));
            asm("v_permlane32_swap_b32 %0, %1" : "+v"(y0), "+v"(y1));
            asm("v_permlane16_swap_b32 %0, %1" : "+v"(x0), "+v"(x1));
            asm("v_permlane16_swap_b32 %0, %1" : "+v"(y0), "+v"(y1));
            union { unsigned int u[4]; bf16x8 v; } pk;
            pk.u[0] = x0; pk.u[1] = y0; pk.u[2] = x1; pk.u[3] = y1;
            bf16x8 ap = pk.v;
            __builtin_amdgcn_s_setprio(1);
#pragma unroll
            for (int di = 0; di < 4; di++) {
                int d = di * 16 + m16;
                int gg = (kst * 4 + quad) ^ (d & 7);
                bf16x8 vf = *(const bf16x8*)&Vt_s[cur][d * 64 + gg * 8];
                o[di] = __builtin_amdgcn_mfma_f32_16x16x32_bf16(
                    vf, ap, o[di], 0, 0, 0);
            }
            __builtin_amdgcn_s_setprio(0);
        }
    }

    // ---- final l reduction + normalize + write ctx [B,S,1024] bf16
    int b = bh >> 4, h = bh & 15;
    float l = l_acc;
    l += __shfl_xor(l, 16);
    l += __shfl_xor(l, 32);
    float rl = 1.0f / l;
    int s = qt * 64 + wave * 16 + m16;
#pragma unroll
    for (int di = 0; di < 4; di++) {
        bf16x4 pk;
#pragma unroll
        for (int r = 0; r < 4; r++) pk[r] = (bf16)(o[di][r] * rl);
        *(bf16x4*)(ctx + ((size_t)b * S_LEN + s) * D_MODEL
                   + h * DHEAD + di * 16 + quad * 4) = pk;
    }
}

// ================================ launch =====================================
extern "C" void kernel_launch(void* const* d_in, const int* in_sizes, int n_in,
                              void* d_out, int out_size, void* d_ws, size_t ws_size,
                              hipStream_t stream) {
    const float* x  = (const float*)d_in[0];
    const float* Wq = (const float*)d_in[1];
    const float* bq = (const float*)d_in[2];
    const float* Wk = (const float*)d_in[3];
    const float* bk = (const float*)d_in[4];
    const float* Wv = (const float*)d_in[5];
    const float* bv = (const float*)d_in[6];
    const float* Wo = (const float*)d_in[7];
    const float* bo = (const float*)d_in[8];
    float* out = (float*)d_out;

    char* ws = (char*)d_ws;
    const size_t MB = 1u << 20;
    bf16* xb  = (bf16*)(ws + 0);         // 8 MB  [4096,1024]
    bf16* Wt  = (bf16*)(ws + 8  * MB);   // 8 MB  [4][1024][1024]
    bf16* Qb  = (bf16*)(ws + 16 * MB);   // 8 MB  [B,H,S,64]  (pre-scaled by QSCALE)
    bf16* Kb  = (bf16*)(ws + 24 * MB);   // 8 MB  [B,H,S,64]
    bf16* Vtb = (bf16*)(ws + 32 * MB);   // 8 MB  [B,H,64,S]
    bf16* ctx = (bf16*)(ws + 0);         // reuse xb region (dead after QKV GEMM)

    prep_kernel<<<dim3(32, 32, 5), dim3(32, 8), 0, stream>>>(x, Wq, Wk, Wv, Wo, xb, Wt);
    gemm_kernel<0><<<dim3(24, 32), 256, 0, stream>>>(xb, Wt, bq, bk, bv,
                                                     Qb, Kb, Vtb, nullptr);
    attn_kernel<<<dim3(32, 32), 256, 0, stream>>>(Qb, Kb, Vtb, ctx);
    gemm_kernel<1><<<dim3(16, 32), 256, 0, stream>>>(ctx, Wt + 3 * 1024 * 1024,
                                                     bo, nullptr, nullptr,
                                                     nullptr, nullptr, nullptr, out);
}

// Round 7
// 177.413 us; speedup vs baseline: 1.0401x; 1.0078x over previous
//
#include <hip/hip_runtime.h>

typedef __bf16 bf16;
typedef __bf16 bf16x8 __attribute__((ext_vector_type(8)));
typedef __bf16 bf16x4 __attribute__((ext_vector_type(4)));
typedef float  f32x4  __attribute__((ext_vector_type(4)));

#define D_MODEL 1024
#define S_LEN   2048
#define NHEAD   16
#define DHEAD   64
#define BATCH   2
#define MROWS   (BATCH * S_LEN)   // 4096

// 0.125 (1/sqrt(dhead)) * log2(e): Q pre-scaled so softmax runs in exp2 domain
#define QSCALE 0.18033688011112042f

// ---- async global->LDS, 16B per lane. lds_base must be wave-uniform; HW
// writes lane i's data at lds_base + i*16 (guide §5 caveat).
__device__ __forceinline__ void gld_lds16(const void* g, void* lds_base) {
    __builtin_amdgcn_global_load_lds(
        (const __attribute__((address_space(1))) void*)g,
        (__attribute__((address_space(3))) void*)lds_base, 16, 0, 0);
}

// ============= prep: transpose+cast 4 weights (z<4) | cast x (z==4) ==========
__global__ void prep_kernel(const float* __restrict__ x,
                            const float* __restrict__ W0, const float* __restrict__ W1,
                            const float* __restrict__ W2, const float* __restrict__ W3,
                            bf16* __restrict__ xb, bf16* __restrict__ Wt) {
    int tx = threadIdx.x, ty = threadIdx.y;   // (32, 8)
    if (blockIdx.z == 4) {
        int tid = ty * 32 + tx;
        size_t base = ((size_t)blockIdx.y * 32 + blockIdx.x) * 4096;
#pragma unroll
        for (int j = 0; j < 4; j++) {
            size_t i = base + (size_t)(j * 256 + tid) * 4;
            f32x4 v = *(const f32x4*)(x + i);
            bf16x4 o;
            o[0] = (bf16)v[0]; o[1] = (bf16)v[1]; o[2] = (bf16)v[2]; o[3] = (bf16)v[3];
            *(bf16x4*)(xb + i) = o;
        }
        return;
    }
    __shared__ float tile[32][33];
    const float* W = (blockIdx.z == 0) ? W0 : (blockIdx.z == 1) ? W1
                   : (blockIdx.z == 2) ? W2 : W3;
    int n0 = blockIdx.x * 32, k0 = blockIdx.y * 32;
#pragma unroll
    for (int j = 0; j < 4; j++)
        tile[ty + 8 * j][tx] = W[(size_t)(k0 + ty + 8 * j) * D_MODEL + n0 + tx];
    __syncthreads();
    bf16* out = Wt + (size_t)blockIdx.z * D_MODEL * D_MODEL;
#pragma unroll
    for (int j = 0; j < 4; j++)
        out[(size_t)(n0 + ty + 8 * j) * D_MODEL + k0 + tx] = (bf16)tile[tx][ty + 8 * j];
}

// ================== gemm0: QKV projections, BK=64 deep steps =================
// BM=128, BN=64, BK=64, 4 waves all on M (per-wave 32x64, acc[2][4]).
// Grid 48x32 = 1536 blocks; LDS 2buf x (16+8)KB = 48 KB -> 3 blocks/CU.
// Round-6 diagnosis: 2-phase stall (MfmaUtil 21%, no pipe >35% busy). BK=64
// halves the barrier count (16 steps) and doubles per-step ILP (16 MFMA +
// 12 ds_read), so each vmcnt(0) drain is amortized over 2x compute.
// Swizzle = the attn K-stage geometry verbatim (64-elem rows): LDS slot s of
// row r holds k-group s ^ (r&7); fragment read slot = (kst*4+quad) ^ (m16&7)
// -> 8 bank-starts x 2 lanes = 2-way = free (measured 0 conflicts in attn).
__global__ __launch_bounds__(256, 3) void gemm0_kernel(
    const bf16* __restrict__ A, const bf16* __restrict__ Bt,
    const float* __restrict__ b0, const float* __restrict__ b1, const float* __restrict__ b2,
    bf16* __restrict__ Qo, bf16* __restrict__ Ko, bf16* __restrict__ Vto) {
    __shared__ bf16 sA[2][128 * 64];
    __shared__ bf16 sB[2][64 * 64];
    const int t = threadIdx.x;
    const int wave = t >> 6, lane = t & 63;
    const int quad = lane >> 4, m16 = lane & 15;
    const int wrow = wave * 32;
    const int row0 = blockIdx.y * 128, col0 = blockIdx.x * 64;
    constexpr int NK = D_MODEL / 64;   // 16

    f32x4 acc[2][4];
#pragma unroll
    for (int i = 0; i < 2; i++)
#pragma unroll
        for (int j = 0; j < 4; j++) acc[i][j] = (f32x4){0.f, 0.f, 0.f, 0.f};

    // stage K-step kk (64-wide) into buffer buf. A: 1024 chunks, B: 512.
    auto stage = [&](int kk, int buf) {
#pragma unroll
        for (int i = 0; i < 4; i++) {
            int cb = i * 256 + wave * 64;       // wave-uniform chunk base
            int c  = cb + lane;
            int r  = c >> 3, sl = c & 7;        // tile row, LDS slot
            int gk = sl ^ (r & 7);              // swizzled global k-group
            gld_lds16(A + (size_t)(row0 + r) * D_MODEL + kk * 64 + gk * 8,
                      (char*)&sA[buf][0] + cb * 16);
        }
#pragma unroll
        for (int i = 0; i < 2; i++) {
            int cb = i * 256 + wave * 64;
            int c  = cb + lane;
            int r  = c >> 3, sl = c & 7;
            int gk = sl ^ (r & 7);
            gld_lds16(Bt + (size_t)(col0 + r) * D_MODEL + kk * 64 + gk * 8,
                      (char*)&sB[buf][0] + cb * 16);
        }
    };

    stage(0, 0);

    const int s7 = m16 & 7;   // row-derived slot swizzle (wave-invariant)
    for (int ks = 0; ks < NK; ++ks) {
        // own stage(ks) landed -> barrier => buf ks&1 staged for all waves;
        // barrier also means everyone finished reading buf (ks+1)&1 (used by
        // compute ks-1), so stage(ks+1) may overwrite it.
        asm volatile("s_waitcnt vmcnt(0)\n\ts_barrier" ::: "memory");
        if (ks + 1 < NK) stage(ks + 1, (ks + 1) & 1);

        const int cur = ks & 1;
        bf16x8 af[2][2], bfr[4][2];
#pragma unroll
        for (int mi = 0; mi < 2; mi++)
#pragma unroll
            for (int kst = 0; kst < 2; kst++) {
                int g = kst * 4 + quad;
                af[mi][kst] = *(const bf16x8*)
                    &sA[cur][(wrow + mi * 16 + m16) * 64 + (g ^ s7) * 8];
            }
#pragma unroll
        for (int ni = 0; ni < 4; ni++)
#pragma unroll
            for (int kst = 0; kst < 2; kst++) {
                int g = kst * 4 + quad;
                bfr[ni][kst] = *(const bf16x8*)
                    &sB[cur][(ni * 16 + m16) * 64 + (g ^ s7) * 8];
            }
#pragma unroll
        for (int kst = 0; kst < 2; kst++)
#pragma unroll
            for (int mi = 0; mi < 2; mi++)
#pragma unroll
                for (int ni = 0; ni < 4; ni++)
                    acc[mi][ni] = __builtin_amdgcn_mfma_f32_16x16x32_bf16(
                        af[mi][kst], bfr[ni][kst], acc[mi][ni], 0, 0, 0);
    }

    // epilogue (C/D: col = lane&15, row = quad*4 + reg; m89-verified).
    int sel = col0 >> 10;   // uniform per block (1024 % 64 == 0)
    const float* bias_arr = (sel == 0) ? b0 : (sel == 1) ? b1 : b2;
#pragma unroll
    for (int mi = 0; mi < 2; mi++) {
        int s0g = row0 + wrow + mi * 16 + quad * 4;   // global M-row base
        int b = s0g >> 11, ss0 = s0g & 2047;
#pragma unroll
        for (int ni = 0; ni < 4; ni++) {
            int col = col0 + ni * 16 + m16;
            int cn = col & 1023;
            int h = cn >> 6, d = cn & 63;
            float bias = bias_arr[cn];
            if (sel < 2) {
                bf16* dst = (sel == 0) ? Qo : Ko;
                float scl = (sel == 0) ? QSCALE : 1.0f;
                size_t base = (((size_t)b * NHEAD + h) * S_LEN);
#pragma unroll
                for (int r = 0; r < 4; r++)
                    dst[(base + ss0 + r) * DHEAD + d] = (bf16)((acc[mi][ni][r] + bias) * scl);
            } else {
                bf16x4 pk;
#pragma unroll
                for (int r = 0; r < 4; r++) pk[r] = (bf16)(acc[mi][ni][r] + bias);
                *(bf16x4*)(Vto + (((size_t)b * NHEAD + h) * DHEAD + d) * S_LEN + ss0) = pk;
            }
        }
    }
}

// ============== gemm1: output projection, intra-block split-K ================
// BM=128, BN=64, BK=32, 512 threads: waves 0-3 (group 0) compute k=[0,512),
// waves 4-7 (group 1) k=[512,1024) on separate staging pipelines sharing the
// per-step barriers (round-6 discipline: triple-buffer, counted vmcnt(3)).
// Round-6 diagnosis: gemm1 at 196 TF, 2 blocks/CU = 2 waves/SIMD, no latency
// hiding. Now: grid 512 blocks x 8 waves -> 2 blocks/CU = 4 waves/SIMD, and
// each wave's K-chain halves (16 steps). Epilogue: group 1 parks its partial
// in an LDS scratch (re-using the staging buffers), group 0 adds + bias.
// LDS: 3buf x 2grp x (8+4)KB = 72 KB -> 2 blocks/CU (= grid limit).
__global__ __launch_bounds__(512, 4) void gemm1_kernel(
    const bf16* __restrict__ A, const bf16* __restrict__ Bt,
    const float* __restrict__ bias, float* __restrict__ Co) {
    __shared__ bf16 sA[3][2][128 * 32];
    __shared__ bf16 sB[3][2][64 * 32];
    const int t = threadIdx.x;
    const int wave = t >> 6, lane = t & 63;
    const int quad = lane >> 4, m16 = lane & 15;
    const int grp = wave >> 2, w4 = wave & 3;
    const int wrow = w4 * 32;
    const int row0 = blockIdx.y * 128, col0 = blockIdx.x * 64;
    const int kbase = grp * 512;
    constexpr int NK = 16;              // 16 x 32 = 512 k per group

    f32x4 acc[2][4];
#pragma unroll
    for (int i = 0; i < 2; i++)
#pragma unroll
        for (int j = 0; j < 4; j++) acc[i][j] = (f32x4){0.f, 0.f, 0.f, 0.f};

    // stage K-step kk of this group's k-half into buffer buf (3 loads/lane:
    // 2 A + 1 B, uniform across all 8 waves -> uniform vmcnt).
    auto stage = [&](int kk, int buf) {
#pragma unroll
        for (int i = 0; i < 2; i++) {
            int cb = i * 256 + w4 * 64;
            int c  = cb + lane;
            int r  = c >> 2, kg = c & 3;
            int gk = kg ^ ((r >> 1) & 3);
            gld_lds16(A + (size_t)(row0 + r) * D_MODEL + kbase + kk * 32 + gk * 8,
                      (char*)&sA[buf][grp][0] + cb * 16);
        }
        {
            int cb = w4 * 64;
            int c  = cb + lane;
            int r  = c >> 2, kg = c & 3;
            int gk = kg ^ ((r >> 1) & 3);
            gld_lds16(Bt + (size_t)(col0 + r) * D_MODEL + kbase + kk * 32 + gk * 8,
                      (char*)&sB[buf][grp][0] + cb * 16);
        }
    };

    stage(0, 0);
    stage(1, 1);

    const int sx = (m16 >> 1) & 3;
    for (int ks = 0; ks < NK; ++ks) {
        if (ks + 1 < NK)
            asm volatile("s_waitcnt vmcnt(3)\n\ts_barrier" ::: "memory");
        else
            asm volatile("s_waitcnt vmcnt(0)\n\ts_barrier" ::: "memory");
        if (ks + 2 < NK) stage(ks + 2, (ks + 2) % 3);

        const int cur = ks % 3;
        const int gg = (quad ^ sx) * 8;
        bf16x8 af[2], bfr[4];
#pragma unroll
        for (int mi = 0; mi < 2; mi++)
            af[mi] = *(const bf16x8*)&sA[cur][grp][(wrow + mi * 16 + m16) * 32 + gg];
#pragma unroll
        for (int ni = 0; ni < 4; ni++)
            bfr[ni] = *(const bf16x8*)&sB[cur][grp][(ni * 16 + m16) * 32 + gg];
#pragma unroll
        for (int mi = 0; mi < 2; mi++)
#pragma unroll
            for (int ni = 0; ni < 4; ni++)
                acc[mi][ni] = __builtin_amdgcn_mfma_f32_16x16x32_bf16(
                    af[mi], bfr[ni], acc[mi][ni], 0, 0, 0);
    }

    // ---- cross-group reduce via LDS scratch (re-uses staging buffers; all
    // LDS reads of the K-loop completed before the first barrier below).
    __syncthreads();
    float* scr = (float*)&sA[0][0][0];   // 128 x 66 f32 = 33.8 KB < 48 KB
    if (grp == 1) {
#pragma unroll
        for (int mi = 0; mi < 2; mi++)
#pragma unroll
            for (int ni = 0; ni < 4; ni++)
#pragma unroll
                for (int r = 0; r < 4; r++)
                    scr[(wrow + mi * 16 + quad * 4 + r) * 66 + ni * 16 + m16] =
                        acc[mi][ni][r];
    }
    __syncthreads();
    if (grp == 0) {
#pragma unroll
        for (int mi = 0; mi < 2; mi++)
#pragma unroll
            for (int ni = 0; ni < 4; ni++) {
                int col = col0 + ni * 16 + m16;
                float bb = bias[col];
#pragma unroll
                for (int r = 0; r < 4; r++) {
                    int row = wrow + mi * 16 + quad * 4 + r;
                    Co[(size_t)(row0 + row) * D_MODEL + col] =
                        acc[mi][ni][r] + scr[row * 66 + ni * 16 + m16] + bb;
                }
            }
    }
}

// ======================= flash attention (causal) ============================
// One block per (head, q-tile): grid 32x32 = 1024 blocks -> 4 blocks/CU.
// Double-buffered KV staging, prefetch depth 1; head->XCD pinning via
// blockIdx.x = bh; LPT via qt = 31-blockIdx.y. Transposed scores, per-lane
// softmax in exp2 domain, in-register P via p32+p16 double swap; V-fragment
// is the conflict-tuned ds_read_b128 from XOR-swizzled Vt_s (0 conflicts).
__global__ __launch_bounds__(256, 4) void attn_kernel(
    const bf16* __restrict__ Q, const bf16* __restrict__ K,
    const bf16* __restrict__ Vt, bf16* __restrict__ ctx) {
    __shared__ bf16 Kt_s[2][64 * 64];
    __shared__ bf16 Vt_s[2][64 * 64];

    const int t = threadIdx.x, wave = t >> 6, lane = t & 63;
    const int quad = lane >> 4, m16 = lane & 15;
    const int bh = blockIdx.x;            // head -> XCD bh%8 (L2 KV locality)
    const int qt = 31 - blockIdx.y;       // big tiles first (LPT)
    const int nt = qt + 1;                // causal KV tiles (64-wide)
    const size_t base = (size_t)bh * S_LEN * DHEAD;

    // Q fragments (B-operand), kept in regs
    bf16x8 aq[2];
#pragma unroll
    for (int kst = 0; kst < 2; kst++)
        aq[kst] = *(const bf16x8*)(Q + base
            + (size_t)(qt * 64 + wave * 16 + m16) * DHEAD + kst * 32 + quad * 8);

    f32x4 o[4];
#pragma unroll
    for (int di = 0; di < 4; di++) o[di] = (f32x4){0.f, 0.f, 0.f, 0.f};
    float l_acc = 0.f;

    auto stage = [&](int j, int buf) {
#pragma unroll
        for (int i = 0; i < 2; i++) {
            int cb = i * 256 + wave * 64;
            int c  = cb + lane;
            int pos = c >> 3, g = c & 7;
            int gk = g ^ (pos & 7);
            gld_lds16(K  + base + (size_t)(j * 64 + pos) * DHEAD + gk * 8,
                      (char*)&Kt_s[buf][0] + cb * 16);
            gld_lds16(Vt + base + (size_t)pos * S_LEN + j * 64 + gk * 8,
                      (char*)&Vt_s[buf][0] + cb * 16);
        }
    };

    stage(0, 0);

    for (int j = 0; j < nt; ++j) {
        asm volatile("s_waitcnt vmcnt(0)\n\ts_barrier" ::: "memory");
        if (j + 1 < nt) stage(j + 1, (j + 1) & 1);

        const int cur = j & 1;
        const int kt0 = j * 64;

        // ---- scores S^T[kpos][q] = K @ Q^T
        f32x4 sc[4];
#pragma unroll
        for (int ni = 0; ni < 4; ni++) sc[ni] = (f32x4){0.f, 0.f, 0.f, 0.f};
        __builtin_amdgcn_s_setprio(1);
#pragma unroll
        for (int ni = 0; ni < 4; ni++) {
            int pos = ni * 16 + m16;
#pragma unroll
            for (int kst = 0; kst < 2; kst++) {
                int gg = (kst * 4 + quad) ^ (pos & 7);
                bf16x8 kf = *(const bf16x8*)&Kt_s[cur][pos * 64 + gg * 8];
                sc[ni] = __builtin_amdgcn_mfma_f32_16x16x32_bf16(
                    kf, aq[kst], sc[ni], 0, 0, 0);
            }
        }
        __builtin_amdgcn_s_setprio(0);

        // ---- causal mask: only on the diagonal tile
        if (j == qt) {
            int qg = qt * 64 + wave * 16 + m16;
#pragma unroll
            for (int ni = 0; ni < 4; ni++)
#pragma unroll
                for (int r = 0; r < 4; r++) {
                    int kp = kt0 + ni * 16 + quad * 4 + r;
                    if (kp > qg) sc[ni][r] = -1e9f;
                }
        }

        // ---- p = exp2(s); accumulate l; pack bf16 dwords in-register.
        unsigned int pd[4][2];
        {
            float ls0 = 0.f, ls1 = 0.f;
#pragma unroll
            for (int ni = 0; ni < 4; ni++) {
                float p0 = __builtin_amdgcn_exp2f(sc[ni][0]);
                float p1 = __builtin_amdgcn_exp2f(sc[ni][1]);
                float p2 = __builtin_amdgcn_exp2f(sc[ni][2]);
                float p3 = __builtin_amdgcn_exp2f(sc[ni][3]);
                union { bf16x4 h; unsigned int u[2]; } cv;
                cv.h[0] = (bf16)p0; cv.h[1] = (bf16)p1;
                cv.h[2] = (bf16)p2; cv.h[3] = (bf16)p3;
                pd[ni][0] = cv.u[0];
                pd[ni][1] = cv.u[1];
                ls0 += p0 + p1;
                ls1 += p2 + p3;
            }
            l_acc += ls0 + ls1;
        }

        // ---- O^T += (P @ V)^T, natural k order via p32+p16 double swap
#pragma unroll
        for (int kst = 0; kst < 2; kst++) {
            unsigned int x0 = pd[2 * kst][0],     y0 = pd[2 * kst][1];
            unsigned int x1 = pd[2 * kst + 1][0], y1 = pd[2 * kst + 1][1];
            asm("v_permlane32_swap_b32 %0, %1" : "+v"(x0), "+v"(x1));
            asm("v_permlane32_swap_b32 %0, %1" : "+v"(y0), "+v"(y1));
            asm("v_permlane16_swap_b32 %0, %1" : "+v"(x0), "+v"(x1));
            asm("v_permlane16_swap_b32 %0, %1" : "+v"(y0), "+v"(y1));
            union { unsigned int u[4]; bf16x8 v; } pk;
            pk.u[0] = x0; pk.u[1] = y0; pk.u[2] = x1; pk.u[3] = y1;
            bf16x8 ap = pk.v;
            __builtin_amdgcn_s_setprio(1);
#pragma unroll
            for (int di = 0; di < 4; di++) {
                int d = di * 16 + m16;
                int gg = (kst * 4 + quad) ^ (d & 7);
                bf16x8 vf = *(const bf16x8*)&Vt_s[cur][d * 64 + gg * 8];
                o[di] = __builtin_amdgcn_mfma_f32_16x16x32_bf16(
                    vf, ap, o[di], 0, 0, 0);
            }
            __builtin_amdgcn_s_setprio(0);
        }
    }

    // ---- final l reduction + normalize + write ctx [B,S,1024] bf16
    int b = bh >> 4, h = bh & 15;
    float l = l_acc;
    l += __shfl_xor(l, 16);
    l += __shfl_xor(l, 32);
    float rl = 1.0f / l;
    int s = qt * 64 + wave * 16 + m16;
#pragma unroll
    for (int di = 0; di < 4; di++) {
        bf16x4 pk;
#pragma unroll
        for (int r = 0; r < 4; r++) pk[r] = (bf16)(o[di][r] * rl);
        *(bf16x4*)(ctx + ((size_t)b * S_LEN + s) * D_MODEL
                   + h * DHEAD + di * 16 + quad * 4) = pk;
    }
}

// ================================ launch =====================================
extern "C" void kernel_launch(void* const* d_in, const int* in_sizes, int n_in,
                              void* d_out, int out_size, void* d_ws, size_t ws_size,
                              hipStream_t stream) {
    const float* x  = (const float*)d_in[0];
    const float* Wq = (const float*)d_in[1];
    const float* bq = (const float*)d_in[2];
    const float* Wk = (const float*)d_in[3];
    const float* bk = (const float*)d_in[4];
    const float* Wv = (const float*)d_in[5];
    const float* bv = (const float*)d_in[6];
    const float* Wo = (const float*)d_in[7];
    const float* bo = (const float*)d_in[8];
    float* out = (float*)d_out;

    char* ws = (char*)d_ws;
    const size_t MB = 1u << 20;
    bf16* xb  = (bf16*)(ws + 0);         // 8 MB  [4096,1024]
    bf16* Wt  = (bf16*)(ws + 8  * MB);   // 8 MB  [4][1024][1024]
    bf16* Qb  = (bf16*)(ws + 16 * MB);   // 8 MB  [B,H,S,64]  (pre-scaled by QSCALE)
    bf16* Kb  = (bf16*)(ws + 24 * MB);   // 8 MB  [B,H,S,64]
    bf16* Vtb = (bf16*)(ws + 32 * MB);   // 8 MB  [B,H,64,S]
    bf16* ctx = (bf16*)(ws + 0);         // reuse xb region (dead after QKV GEMM)

    prep_kernel<<<dim3(32, 32, 5), dim3(32, 8), 0, stream>>>(x, Wq, Wk, Wv, Wo, xb, Wt);
    gemm0_kernel<<<dim3(48, 32), 256, 0, stream>>>(xb, Wt, bq, bk, bv,
                                                   Qb, Kb, Vtb);
    attn_kernel<<<dim3(32, 32), 256, 0, stream>>>(Qb, Kb, Vtb, ctx);
    gemm1_kernel<<<dim3(16, 32), 512, 0, stream>>>(ctx, Wt + 3 * 1024 * 1024,
                                                   bo, out);
}